// Round 1
// baseline (1017.065 us; speedup 1.0000x reference)
//
#include <hip/hip_runtime.h>

#define NN 100000
#define NE 6400000

// ---------------- kernels ----------------

__global__ void deg_kernel(const int* __restrict__ col, float* __restrict__ deg, int E) {
    int stride = gridDim.x * blockDim.x;
    for (int i = blockIdx.x * blockDim.x + threadIdx.x; i < E; i += stride)
        atomicAdd(&deg[col[i]], 1.0f);
}

__global__ void dinv_kernel(float* __restrict__ deg_inout, int N) {
    int stride = gridDim.x * blockDim.x;
    for (int i = blockIdx.x * blockDim.x + threadIdx.x; i < N; i += stride) {
        float d = deg_inout[i] + 1.0f;   // +1 self-loop
        deg_inout[i] = rsqrtf(d);
    }
}

// h1_pre[i][f] = sum_k x[i][k] * W1[k][f]   (9 -> 16)
__global__ void h1pre_kernel(const float* __restrict__ x, const float* __restrict__ W1,
                             float* __restrict__ h1p, int N) {
    __shared__ float sW[9 * 16];
    if (threadIdx.x < 9 * 16) sW[threadIdx.x] = W1[threadIdx.x];
    __syncthreads();
    int stride = gridDim.x * blockDim.x;
    for (int i = blockIdx.x * blockDim.x + threadIdx.x; i < N; i += stride) {
        float xi[9];
#pragma unroll
        for (int k = 0; k < 9; ++k) xi[k] = x[i * 9 + k];
#pragma unroll
        for (int f = 0; f < 16; ++f) {
            float acc = 0.f;
#pragma unroll
            for (int k = 0; k < 9; ++k) acc = fmaf(xi[k], sW[k * 16 + f], acc);
            h1p[i * 16 + f] = acc;
        }
    }
}

// agg1[col][f] += h1p[row][f] * dinv[row]*dinv[col]   (16 threads per edge)
__global__ void scatter1_kernel(const int* __restrict__ row, const int* __restrict__ col,
                                const float* __restrict__ dinv, const float* __restrict__ h1p,
                                float* __restrict__ agg1, long total) {
    long stride = (long)gridDim.x * blockDim.x;
    for (long t = (long)blockIdx.x * blockDim.x + threadIdx.x; t < total; t += stride) {
        int e = (int)(t >> 4);
        int f = (int)(t & 15);
        int r = row[e], c = col[e];
        float nrm = dinv[r] * dinv[c];
        atomicAdd(&agg1[c * 16 + f], h1p[r * 16 + f] * nrm);
    }
}

// h1 = relu(agg1 + h1p*dinv^2 + b1); h2_pre = h1 . W2
__global__ void finalize1_kernel(const float* __restrict__ agg1, const float* __restrict__ h1p,
                                 const float* __restrict__ dinv, const float* __restrict__ b1,
                                 const float* __restrict__ W2, float* __restrict__ h2p, int N) {
    __shared__ float sW2[16], sb1[16];
    if (threadIdx.x < 16) { sW2[threadIdx.x] = W2[threadIdx.x]; sb1[threadIdx.x] = b1[threadIdx.x]; }
    __syncthreads();
    int stride = gridDim.x * blockDim.x;
    for (int i = blockIdx.x * blockDim.x + threadIdx.x; i < N; i += stride) {
        float di = dinv[i];
        float self = di * di;
        float acc = 0.f;
#pragma unroll
        for (int f = 0; f < 16; ++f) {
            float v = agg1[i * 16 + f] + h1p[i * 16 + f] * self + sb1[f];
            v = fmaxf(v, 0.f);
            acc = fmaf(v, sW2[f], acc);
        }
        h2p[i] = acc;
    }
}

// out[col] += h2p[row] * dinv[row]*dinv[col]
__global__ void scatter2_kernel(const int* __restrict__ row, const int* __restrict__ col,
                                const float* __restrict__ dinv, const float* __restrict__ h2p,
                                float* __restrict__ out, int E) {
    int stride = gridDim.x * blockDim.x;
    for (int e = blockIdx.x * blockDim.x + threadIdx.x; e < E; e += stride) {
        int r = row[e], c = col[e];
        atomicAdd(&out[c], h2p[r] * dinv[r] * dinv[c]);
    }
}

__global__ void finalize2_kernel(float* __restrict__ out, const float* __restrict__ h2p,
                                 const float* __restrict__ dinv, const float* __restrict__ b2, int N) {
    float b = b2[0];
    int stride = gridDim.x * blockDim.x;
    for (int i = blockIdx.x * blockDim.x + threadIdx.x; i < N; i += stride) {
        float di = dinv[i];
        float v = out[i] + h2p[i] * di * di + b;
        out[i] = fmaxf(v, 0.f);
    }
}

// ---------------- launcher ----------------

extern "C" void kernel_launch(void* const* d_in, const int* in_sizes, int n_in,
                              void* d_out, int out_size, void* d_ws, size_t ws_size,
                              hipStream_t stream) {
    const float* x  = (const float*)d_in[0];
    const int*   ei = (const int*)d_in[1];   // [2, NE] -> row = ei, col = ei + NE
    const float* W1 = (const float*)d_in[2];
    const float* b1 = (const float*)d_in[3];
    const float* W2 = (const float*)d_in[4];
    const float* b2 = (const float*)d_in[5];
    float* out = (float*)d_out;

    const int* row = ei;
    const int* col = ei + NE;

    char* ws = (char*)d_ws;
    // layout (bytes): dinv [0, 400000) ; h1p [524288, +6.4MB) ; agg1 [6924288, +6.4MB) ; h2p [13324288, +400000)
    float* dinv = (float*)(ws);
    float* h1p  = (float*)(ws + 524288);
    float* agg1 = (float*)(ws + 6924288);
    float* h2p  = (float*)(ws + 13324288);

    hipMemsetAsync(dinv, 0, NN * sizeof(float), stream);
    hipMemsetAsync(agg1, 0, NN * 16 * sizeof(float), stream);
    hipMemsetAsync(out, 0, NN * sizeof(float), stream);

    const int B = 256;
    int gridE  = 4096;                    // grid-stride over edges
    int gridN  = (NN + B - 1) / B;        // one thread per node
    int gridE16 = 8192;                   // grid-stride over 16*E work items

    deg_kernel<<<gridE, B, 0, stream>>>(col, dinv, NE);
    dinv_kernel<<<gridN, B, 0, stream>>>(dinv, NN);
    h1pre_kernel<<<gridN, B, 0, stream>>>(x, W1, h1p, NN);
    scatter1_kernel<<<gridE16, B, 0, stream>>>(row, col, dinv, h1p, agg1, (long)NE * 16);
    finalize1_kernel<<<gridN, B, 0, stream>>>(agg1, h1p, dinv, b1, W2, h2p, NN);
    scatter2_kernel<<<gridE, B, 0, stream>>>(row, col, dinv, h2p, out, NE);
    finalize2_kernel<<<gridN, B, 0, stream>>>(out, h2p, dinv, b2, NN);
}

// Round 2
// 843.899 us; speedup vs baseline: 1.2052x; 1.2052x over previous
//
#include <hip/hip_runtime.h>

#define NN 100000
#define NE 6400000
#define BSZ 128                 // nodes per bucket
#define NBKT 782                // ceil(NN/BSZ)
#define NB 512                  // sort blocks
#define CHUNK 12500             // NE/NB exactly
#define TOTBINS (NBKT * NB)     // 400384
#define NCH 391                 // TOTBINS / 1024 exactly

// ============================ fast path ============================

__global__ __launch_bounds__(256) void histA(const int* __restrict__ col, int* __restrict__ H) {
    __shared__ int h[NBKT];
    for (int i = threadIdx.x; i < NBKT; i += 256) h[i] = 0;
    __syncthreads();
    const int* c = col + blockIdx.x * CHUNK;
    for (int i = threadIdx.x; i < CHUNK; i += 256)
        atomicAdd(&h[c[i] >> 7], 1);
    __syncthreads();
    int* out = H + blockIdx.x * NBKT;
    for (int i = threadIdx.x; i < NBKT; i += 256) out[i] = h[i];
}

// scan chunk of 1024 bins in order idx = k*NB + b, gathered from H[b*NBKT + k]
__global__ __launch_bounds__(256) void scan1(const int* __restrict__ H, int* __restrict__ S1,
                                             int* __restrict__ ctot) {
    __shared__ int buf[1024];
    __shared__ int ts[256];
    int base = blockIdx.x * 1024;
    for (int j = threadIdx.x; j < 1024; j += 256) {
        int idx = base + j;
        int k = idx >> 9;        // / NB
        int b = idx & (NB - 1);
        buf[j] = H[b * NBKT + k];
    }
    __syncthreads();
    int j0 = threadIdx.x * 4;
    int a0 = buf[j0], a1 = buf[j0 + 1], a2 = buf[j0 + 2], a3 = buf[j0 + 3];
    int s = a0 + a1 + a2 + a3;
    ts[threadIdx.x] = s;
    __syncthreads();
    for (int off = 1; off < 256; off <<= 1) {
        int u = (threadIdx.x >= off) ? ts[threadIdx.x - off] : 0;
        __syncthreads();
        ts[threadIdx.x] += u;
        __syncthreads();
    }
    int ebase = ts[threadIdx.x] - s;   // exclusive base for this thread's 4 elems
    S1[base + j0]     = ebase;
    S1[base + j0 + 1] = ebase + a0;
    S1[base + j0 + 2] = ebase + a0 + a1;
    S1[base + j0 + 3] = ebase + a0 + a1 + a2;
    if (threadIdx.x == 255) ctot[blockIdx.x] = ts[255];
}

__global__ void scan2(const int* __restrict__ ctot, int* __restrict__ cbase) {
    __shared__ int ts[512];
    int t = threadIdx.x;
    int orig = (t < NCH) ? ctot[t] : 0;
    ts[t] = orig;
    __syncthreads();
    for (int off = 1; off < 512; off <<= 1) {
        int u = (t >= off) ? ts[t - off] : 0;
        __syncthreads();
        ts[t] += u;
        __syncthreads();
    }
    if (t < NCH) cbase[t] = ts[t] - orig;  // exclusive
}

// final = S1 + cbase, stored transposed: ST[b*NBKT + k]
__global__ __launch_bounds__(256) void scan3(const int* __restrict__ S1, const int* __restrict__ cbase,
                                             int* __restrict__ ST) {
    int base = blockIdx.x * 1024;
    int cb = cbase[blockIdx.x];
    for (int j = threadIdx.x; j < 1024; j += 256) {
        int idx = base + j;
        int k = idx >> 9;
        int b = idx & (NB - 1);
        ST[b * NBKT + k] = S1[idx] + cb;
    }
}

__global__ __launch_bounds__(256) void passB(const int* __restrict__ row, const int* __restrict__ col,
                                             const int* __restrict__ ST, int* __restrict__ eb) {
    __shared__ int cur[NBKT];
    const int* st = ST + blockIdx.x * NBKT;
    for (int i = threadIdx.x; i < NBKT; i += 256) cur[i] = st[i];
    __syncthreads();
    const int* r = row + blockIdx.x * CHUNK;
    const int* c = col + blockIdx.x * CHUNK;
    for (int i = threadIdx.x; i < CHUNK; i += 256) {
        int cc = c[i];
        int pos = atomicAdd(&cur[cc >> 7], 1);
        eb[pos] = r[i] | ((cc & 127) << 17);
    }
}

__global__ __launch_bounds__(256) void passC(const int* __restrict__ eb, const int* __restrict__ ST,
                                             float* __restrict__ dinv) {
    __shared__ int cnt[BSZ];
    int k = blockIdx.x;
    if (threadIdx.x < BSZ) cnt[threadIdx.x] = 0;
    int s = ST[k];
    int e = (k + 1 < NBKT) ? ST[k + 1] : NE;
    __syncthreads();
    for (int i = s + threadIdx.x; i < e; i += 256)
        atomicAdd(&cnt[eb[i] >> 17], 1);
    __syncthreads();
    if (threadIdx.x < BSZ) {
        int node = k * BSZ + threadIdx.x;
        if (node < NN) dinv[node] = rsqrtf((float)cnt[threadIdx.x] + 1.0f);
    }
}

// g1[i][f] = dinv[i] * (x[i] @ W1)[f]
__global__ __launch_bounds__(256) void passD(const float* __restrict__ x, const float* __restrict__ W1,
                                             const float* __restrict__ dinv, float* __restrict__ g1) {
    __shared__ float sW[144];
    if (threadIdx.x < 144) sW[threadIdx.x] = W1[threadIdx.x];
    __syncthreads();
    int i = blockIdx.x * 256 + threadIdx.x;
    if (i >= NN) return;
    float xi[9];
#pragma unroll
    for (int q = 0; q < 9; ++q) xi[q] = x[i * 9 + q];
    float di = dinv[i];
#pragma unroll
    for (int f = 0; f < 16; ++f) {
        float acc = 0.f;
#pragma unroll
        for (int q = 0; q < 9; ++q) acc = fmaf(xi[q], sW[q * 16 + f], acc);
        g1[(i << 4) + f] = acc * di;
    }
}

// layer1 aggregate + finalize + layer2 GEMV:  gg[c] = dinv[c] * (relu(dinv[c]*(sum g1[r] + g1[c]) + b1) . W2)
__global__ __launch_bounds__(256) void passE(const int* __restrict__ eb, const int* __restrict__ ST,
                                             const float* __restrict__ g1, const float* __restrict__ dinv,
                                             const float* __restrict__ b1, const float* __restrict__ W2,
                                             float* __restrict__ gg) {
    __shared__ float acc[BSZ * 16];
    __shared__ float sb1[16], sW2[16];
    int k = blockIdx.x;
    for (int i = threadIdx.x; i < BSZ * 16; i += 256) acc[i] = 0.f;
    if (threadIdx.x < 16) { sb1[threadIdx.x] = b1[threadIdx.x]; sW2[threadIdx.x] = W2[threadIdx.x]; }
    int s = ST[k];
    int e = (k + 1 < NBKT) ? ST[k + 1] : NE;
    __syncthreads();
    int f  = threadIdx.x & 15;
    int es = threadIdx.x >> 4;        // 16 edges in flight per block iteration
    for (int i = s + es; i < e; i += 16) {
        int p = eb[i];
        int r = p & 0x1FFFF;
        atomicAdd(&acc[((p >> 17) << 4) + f], g1[(r << 4) + f]);
    }
    __syncthreads();
    if (threadIdx.x < BSZ) {
        int node = k * BSZ + threadIdx.x;
        if (node < NN) {
            float di = dinv[node];
            float h2 = 0.f;
#pragma unroll
            for (int ff = 0; ff < 16; ++ff) {
                float v = di * (acc[(threadIdx.x << 4) + ff] + g1[(node << 4) + ff]) + sb1[ff];
                v = fmaxf(v, 0.f);
                h2 = fmaf(v, sW2[ff], h2);
            }
            gg[node] = di * h2;
        }
    }
}

__global__ __launch_bounds__(256) void passF(const int* __restrict__ eb, const int* __restrict__ ST,
                                             const float* __restrict__ gg, const float* __restrict__ dinv,
                                             const float* __restrict__ b2, float* __restrict__ out) {
    __shared__ float acc[BSZ];
    int k = blockIdx.x;
    if (threadIdx.x < BSZ) acc[threadIdx.x] = 0.f;
    int s = ST[k];
    int e = (k + 1 < NBKT) ? ST[k + 1] : NE;
    __syncthreads();
    for (int i = s + threadIdx.x; i < e; i += 256) {
        int p = eb[i];
        atomicAdd(&acc[p >> 17], gg[p & 0x1FFFF]);
    }
    __syncthreads();
    if (threadIdx.x < BSZ) {
        int node = k * BSZ + threadIdx.x;
        if (node < NN)
            out[node] = fmaxf(dinv[node] * (acc[threadIdx.x] + gg[node]) + b2[0], 0.f);
    }
}

// ============================ fallback path (global atomics) ============================

__global__ void fb_deg(const int* __restrict__ col, float* __restrict__ deg, int E) {
    int stride = gridDim.x * blockDim.x;
    for (int i = blockIdx.x * blockDim.x + threadIdx.x; i < E; i += stride)
        atomicAdd(&deg[col[i]], 1.0f);
}
__global__ void fb_dinv(float* __restrict__ d, int N) {
    int i = blockIdx.x * blockDim.x + threadIdx.x;
    if (i < N) d[i] = rsqrtf(d[i] + 1.0f);
}
__global__ void fb_h1p(const float* __restrict__ x, const float* __restrict__ W1, float* __restrict__ h1p, int N) {
    __shared__ float sW[144];
    if (threadIdx.x < 144) sW[threadIdx.x] = W1[threadIdx.x];
    __syncthreads();
    int i = blockIdx.x * blockDim.x + threadIdx.x;
    if (i >= N) return;
    float xi[9];
#pragma unroll
    for (int q = 0; q < 9; ++q) xi[q] = x[i * 9 + q];
#pragma unroll
    for (int ff = 0; ff < 16; ++ff) {
        float a = 0.f;
#pragma unroll
        for (int q = 0; q < 9; ++q) a = fmaf(xi[q], sW[q * 16 + ff], a);
        h1p[i * 16 + ff] = a;
    }
}
__global__ void fb_sc1(const int* __restrict__ row, const int* __restrict__ col, const float* __restrict__ dinv,
                       const float* __restrict__ h1p, float* __restrict__ agg1, long total) {
    long stride = (long)gridDim.x * blockDim.x;
    for (long t = (long)blockIdx.x * blockDim.x + threadIdx.x; t < total; t += stride) {
        int e = (int)(t >> 4), ff = (int)(t & 15);
        int r = row[e], c = col[e];
        atomicAdd(&agg1[c * 16 + ff], h1p[r * 16 + ff] * dinv[r] * dinv[c]);
    }
}
__global__ void fb_fin1(const float* __restrict__ agg1, const float* __restrict__ h1p, const float* __restrict__ dinv,
                        const float* __restrict__ b1, const float* __restrict__ W2, float* __restrict__ h2p, int N) {
    __shared__ float sW2[16], sb1[16];
    if (threadIdx.x < 16) { sW2[threadIdx.x] = W2[threadIdx.x]; sb1[threadIdx.x] = b1[threadIdx.x]; }
    __syncthreads();
    int i = blockIdx.x * blockDim.x + threadIdx.x;
    if (i >= N) return;
    float di = dinv[i], self = di * di, a = 0.f;
#pragma unroll
    for (int ff = 0; ff < 16; ++ff) {
        float v = agg1[i * 16 + ff] + h1p[i * 16 + ff] * self + sb1[ff];
        a = fmaf(fmaxf(v, 0.f), sW2[ff], a);
    }
    h2p[i] = a;
}
__global__ void fb_sc2(const int* __restrict__ row, const int* __restrict__ col, const float* __restrict__ dinv,
                       const float* __restrict__ h2p, float* __restrict__ out, int E) {
    int stride = gridDim.x * blockDim.x;
    for (int e = blockIdx.x * blockDim.x + threadIdx.x; e < E; e += stride) {
        int r = row[e], c = col[e];
        atomicAdd(&out[c], h2p[r] * dinv[r] * dinv[c]);
    }
}
__global__ void fb_fin2(float* __restrict__ out, const float* __restrict__ h2p, const float* __restrict__ dinv,
                        const float* __restrict__ b2, int N) {
    int i = blockIdx.x * blockDim.x + threadIdx.x;
    if (i < N) {
        float di = dinv[i];
        out[i] = fmaxf(out[i] + h2p[i] * di * di + b2[0], 0.f);
    }
}

// ============================ launcher ============================

extern "C" void kernel_launch(void* const* d_in, const int* in_sizes, int n_in,
                              void* d_out, int out_size, void* d_ws, size_t ws_size,
                              hipStream_t stream) {
    const float* x  = (const float*)d_in[0];
    const int*   ei = (const int*)d_in[1];
    const float* W1 = (const float*)d_in[2];
    const float* b1 = (const float*)d_in[3];
    const float* W2 = (const float*)d_in[4];
    const float* b2 = (const float*)d_in[5];
    float* out = (float*)d_out;
    const int* row = ei;
    const int* col = ei + NE;
    char* ws = (char*)d_ws;

    constexpr size_t OFF_EB = 0;                     // 25,600,000 B
    constexpr size_t OFF_H  = 25600000;              // 1,602,048 B (padded)
    constexpr size_t OFF_S1 = OFF_H + 1602048;
    constexpr size_t OFF_ST = OFF_S1 + 1602048;
    constexpr size_t OFF_CT = OFF_ST + 1602048;      // 2048 B
    constexpr size_t OFF_CB = OFF_CT + 2048;         // 2048 B
    constexpr size_t OFF_DI = OFF_CB + 2048;         // 400,128 B
    constexpr size_t OFF_G1 = OFF_DI + 400128;       // 6,400,000 B
    constexpr size_t OFF_GG = OFF_G1 + 6400000;      // 400,000 B
    constexpr size_t WS_NEED = OFF_GG + 400000;      // ~37.6 MB

    if (ws_size >= WS_NEED) {
        int*   eb    = (int*)(ws + OFF_EB);
        int*   H     = (int*)(ws + OFF_H);
        int*   S1    = (int*)(ws + OFF_S1);
        int*   ST    = (int*)(ws + OFF_ST);
        int*   ctot  = (int*)(ws + OFF_CT);
        int*   cbase = (int*)(ws + OFF_CB);
        float* dinv  = (float*)(ws + OFF_DI);
        float* g1    = (float*)(ws + OFF_G1);
        float* gg    = (float*)(ws + OFF_GG);

        histA<<<NB, 256, 0, stream>>>(col, H);
        scan1<<<NCH, 256, 0, stream>>>(H, S1, ctot);
        scan2<<<1, 512, 0, stream>>>(ctot, cbase);
        scan3<<<NCH, 256, 0, stream>>>(S1, cbase, ST);
        passB<<<NB, 256, 0, stream>>>(row, col, ST, eb);
        passC<<<NBKT, 256, 0, stream>>>(eb, ST, dinv);
        passD<<<(NN + 255) / 256, 256, 0, stream>>>(x, W1, dinv, g1);
        passE<<<NBKT, 256, 0, stream>>>(eb, ST, g1, dinv, b1, W2, gg);
        passF<<<NBKT, 256, 0, stream>>>(eb, ST, gg, dinv, b2, out);
    } else {
        // fallback: global-atomic version (needs ~13.8 MB)
        float* dinv = (float*)(ws);
        float* h1p  = (float*)(ws + 524288);
        float* agg1 = (float*)(ws + 6924288);
        float* h2p  = (float*)(ws + 13324288);
        hipMemsetAsync(dinv, 0, NN * sizeof(float), stream);
        hipMemsetAsync(agg1, 0, NN * 16 * sizeof(float), stream);
        hipMemsetAsync(out, 0, NN * sizeof(float), stream);
        const int B = 256;
        int gridN = (NN + B - 1) / B;
        fb_deg<<<4096, B, 0, stream>>>(col, dinv, NE);
        fb_dinv<<<gridN, B, 0, stream>>>(dinv, NN);
        fb_h1p<<<gridN, B, 0, stream>>>(x, W1, h1p, NN);
        fb_sc1<<<8192, B, 0, stream>>>(row, col, dinv, h1p, agg1, (long)NE * 16);
        fb_fin1<<<gridN, B, 0, stream>>>(agg1, h1p, dinv, b1, W2, h2p, NN);
        fb_sc2<<<4096, B, 0, stream>>>(row, col, dinv, h2p, out, NE);
        fb_fin2<<<gridN, B, 0, stream>>>(out, h2p, dinv, b2, NN);
    }
}

// Round 3
// 743.461 us; speedup vs baseline: 1.3680x; 1.1351x over previous
//
#include <hip/hip_runtime.h>

#define NN 100000
#define NE 6400000
#define BSZ 64                   // nodes per bucket
#define NBKT 1563                // ceil(NN/BSZ)
#define NB 512                   // sort blocks
#define CHUNK 12500              // NE/NB exactly
#define TOTBINS (NBKT * NB)      // 800256
#define NCH 782                  // ceil(TOTBINS/1024)
#define PADS 17                  // padded LDS row stride (bank-conflict fix)

// ============================ fast path ============================

// X[b*NBKT + k] = count of edges in chunk b destined to bucket k
__global__ __launch_bounds__(512) void histA(const int* __restrict__ col, int* __restrict__ X) {
    __shared__ int h[NBKT];
    for (int i = threadIdx.x; i < NBKT; i += 512) h[i] = 0;
    __syncthreads();
    const int* c = col + blockIdx.x * CHUNK;
    for (int i = threadIdx.x; i < CHUNK; i += 512)
        atomicAdd(&h[c[i] >> 6], 1);
    __syncthreads();
    int* o = X + blockIdx.x * NBKT;
    for (int i = threadIdx.x; i < NBKT; i += 512) o[i] = h[i];
}

// in-place exclusive scan of X over logical order idx = k*NB + b, chunked by 1024
__global__ __launch_bounds__(256) void scan1(int* __restrict__ X, int* __restrict__ ctot) {
    __shared__ int buf[1024];
    __shared__ int ts[256];
    int base = blockIdx.x << 10;
    for (int j = threadIdx.x; j < 1024; j += 256) {
        int idx = base + j;
        int v = 0;
        if (idx < TOTBINS) {
            int k = idx >> 9, b = idx & 511;
            v = X[b * NBKT + k];
        }
        buf[j] = v;
    }
    __syncthreads();
    int j0 = threadIdx.x * 4;
    int a0 = buf[j0], a1 = buf[j0 + 1], a2 = buf[j0 + 2], a3 = buf[j0 + 3];
    int s = a0 + a1 + a2 + a3;
    ts[threadIdx.x] = s;
    __syncthreads();
    for (int off = 1; off < 256; off <<= 1) {
        int u = (threadIdx.x >= off) ? ts[threadIdx.x - off] : 0;
        __syncthreads();
        ts[threadIdx.x] += u;
        __syncthreads();
    }
    int eb0 = ts[threadIdx.x] - s;     // exclusive base of this thread's 4 elems
    int ev[4] = {eb0, eb0 + a0, eb0 + a0 + a1, eb0 + a0 + a1 + a2};
#pragma unroll
    for (int t = 0; t < 4; ++t) {
        int idx = base + j0 + t;
        if (idx < TOTBINS) {
            int k = idx >> 9, b = idx & 511;
            X[b * NBKT + k] = ev[t];
        }
    }
    if (threadIdx.x == 255) ctot[blockIdx.x] = ts[255];
}

__global__ void scan2(const int* __restrict__ ctot, int* __restrict__ cbase) {
    __shared__ int ts[1024];
    int t = threadIdx.x;
    int orig = (t < NCH) ? ctot[t] : 0;
    ts[t] = orig;
    __syncthreads();
    for (int off = 1; off < 1024; off <<= 1) {
        int u = (t >= off) ? ts[t - off] : 0;
        __syncthreads();
        ts[t] += u;
        __syncthreads();
    }
    if (t < NCH) cbase[t] = ts[t] - orig;   // exclusive
}

// X[m] += cbase[chunk(idx(m))]  — elementwise, finishes global offsets in place
__global__ __launch_bounds__(256) void scan3(int* __restrict__ X, const int* __restrict__ cbase) {
    int m = blockIdx.x * 256 + threadIdx.x;
    if (m >= TOTBINS) return;
    int b = m / NBKT;
    int k = m - b * NBKT;
    int idx = (k << 9) | b;
    X[m] += cbase[idx >> 10];
}

// scatter edges into bucket-sorted eb; pack (slot<<17 | row)
__global__ __launch_bounds__(512) void passB(const int* __restrict__ row, const int* __restrict__ col,
                                             const int* __restrict__ X, int* __restrict__ eb) {
    __shared__ int cur[NBKT];
    const int* st = X + blockIdx.x * NBKT;
    for (int i = threadIdx.x; i < NBKT; i += 512) cur[i] = st[i];
    __syncthreads();
    const int* r = row + blockIdx.x * CHUNK;
    const int* c = col + blockIdx.x * CHUNK;
    for (int i = threadIdx.x; i < CHUNK; i += 512) {
        int cc = c[i];
        int pos = atomicAdd(&cur[cc >> 6], 1);
        eb[pos] = r[i] | ((cc & 63) << 17);
    }
}

// degree -> dinv, fused with g1[i][f] = dinv[i] * (x[i] @ W1)[f]
__global__ __launch_bounds__(256) void passC(const int* __restrict__ eb, const int* __restrict__ X,
                                             const float* __restrict__ x, const float* __restrict__ W1,
                                             float* __restrict__ dinv, float* __restrict__ g1) {
    __shared__ int cnt[BSZ];
    __shared__ float sW[144];
    int k = blockIdx.x;
    if (threadIdx.x < BSZ) cnt[threadIdx.x] = 0;
    for (int i = threadIdx.x; i < 144; i += 256) sW[i] = W1[i];
    int s = X[k];
    int e = (k + 1 < NBKT) ? X[k + 1] : NE;
    __syncthreads();
    {
        int i = s + (int)threadIdx.x;
        int nIter = (e - s + 255) >> 8;
        int p = (i < e) ? eb[i] : -1;
        for (int t = 0; t < nIter; ++t) {
            int inext = i + 256;
            int pnext = (inext < e) ? eb[inext] : -1;
            if (p >= 0) atomicAdd(&cnt[p >> 17], 1);
            p = pnext; i = inext;
        }
    }
    __syncthreads();
    int node0 = k * BSZ;
    if (threadIdx.x < BSZ) {
        int node = node0 + threadIdx.x;
        if (node < NN) dinv[node] = rsqrtf((float)cnt[threadIdx.x] + 1.0f);
    }
    int ln = threadIdx.x >> 2;            // 0..63
    int node = node0 + ln;
    if (node < NN) {
        float di = rsqrtf((float)cnt[ln] + 1.0f);
        int fq = (threadIdx.x & 3) << 2;  // 0,4,8,12
        float xr[9];
#pragma unroll
        for (int q = 0; q < 9; ++q) xr[q] = x[node * 9 + q];
#pragma unroll
        for (int j = 0; j < 4; ++j) {
            int f = fq + j;
            float a = 0.f;
#pragma unroll
            for (int q = 0; q < 9; ++q) a = fmaf(xr[q], sW[q * 16 + f], a);
            g1[(node << 4) + f] = a * di;
        }
    }
}

// layer1 aggregate + relu + layer2 GEMV: gg[c] = dinv[c]*(relu(dinv[c]*(sum g1[r] + g1[c]) + b1).W2)
__global__ __launch_bounds__(256) void passE(const int* __restrict__ eb, const int* __restrict__ X,
                                             const float* __restrict__ g1, const float* __restrict__ dinv,
                                             const float* __restrict__ b1, const float* __restrict__ W2,
                                             float* __restrict__ gg) {
    __shared__ float acc[BSZ * PADS];     // 4352 B, stride-17 padded
    __shared__ float sb1[16], sW2[16];
    int k = blockIdx.x;
    for (int i = threadIdx.x; i < BSZ * PADS; i += 256) acc[i] = 0.f;
    if (threadIdx.x < 16) { sb1[threadIdx.x] = b1[threadIdx.x]; sW2[threadIdx.x] = W2[threadIdx.x]; }
    int s = X[k];
    int e = (k + 1 < NBKT) ? X[k + 1] : NE;
    __syncthreads();
    int nIter = (e - s + 255) >> 8;
    int i = s + (int)threadIdx.x;
    int p = (i < e) ? eb[i] : -1;
    for (int t = 0; t < nIter; ++t) {
        int inext = i + 256;
        int pnext = (inext < e) ? eb[inext] : -1;
        if (p >= 0) {
            int r = p & 0x1FFFF;
            int slot = p >> 17;
            const float4* gp = (const float4*)(g1 + (r << 4));
            float4 v0 = gp[0], v1 = gp[1], v2 = gp[2], v3 = gp[3];
            float* a = acc + slot * PADS;
            atomicAdd(a + 0,  v0.x); atomicAdd(a + 1,  v0.y);
            atomicAdd(a + 2,  v0.z); atomicAdd(a + 3,  v0.w);
            atomicAdd(a + 4,  v1.x); atomicAdd(a + 5,  v1.y);
            atomicAdd(a + 6,  v1.z); atomicAdd(a + 7,  v1.w);
            atomicAdd(a + 8,  v2.x); atomicAdd(a + 9,  v2.y);
            atomicAdd(a + 10, v2.z); atomicAdd(a + 11, v2.w);
            atomicAdd(a + 12, v3.x); atomicAdd(a + 13, v3.y);
            atomicAdd(a + 14, v3.z); atomicAdd(a + 15, v3.w);
        }
        p = pnext; i = inext;
    }
    __syncthreads();
    if (threadIdx.x < BSZ) {
        int node = k * BSZ + threadIdx.x;
        if (node < NN) {
            float di = dinv[node];
            float h2 = 0.f;
#pragma unroll
            for (int ff = 0; ff < 16; ++ff) {
                float v = di * (acc[threadIdx.x * PADS + ff] + g1[(node << 4) + ff]) + sb1[ff];
                h2 = fmaf(fmaxf(v, 0.f), sW2[ff], h2);
            }
            gg[node] = di * h2;
        }
    }
}

// layer2 aggregate + finalize
__global__ __launch_bounds__(256) void passF(const int* __restrict__ eb, const int* __restrict__ X,
                                             const float* __restrict__ gg, const float* __restrict__ dinv,
                                             const float* __restrict__ b2, float* __restrict__ out) {
    __shared__ float acc[BSZ];
    int k = blockIdx.x;
    if (threadIdx.x < BSZ) acc[threadIdx.x] = 0.f;
    int s = X[k];
    int e = (k + 1 < NBKT) ? X[k + 1] : NE;
    __syncthreads();
    int nIter = (e - s + 255) >> 8;
    int i = s + (int)threadIdx.x;
    int p = (i < e) ? eb[i] : -1;
    for (int t = 0; t < nIter; ++t) {
        int inext = i + 256;
        int pnext = (inext < e) ? eb[inext] : -1;
        if (p >= 0) atomicAdd(&acc[p >> 17], gg[p & 0x1FFFF]);
        p = pnext; i = inext;
    }
    __syncthreads();
    if (threadIdx.x < BSZ) {
        int node = k * BSZ + threadIdx.x;
        if (node < NN)
            out[node] = fmaxf(dinv[node] * (acc[threadIdx.x] + gg[node]) + b2[0], 0.f);
    }
}

// ============================ fallback path (global atomics) ============================

__global__ void fb_deg(const int* __restrict__ col, float* __restrict__ deg, int E) {
    int stride = gridDim.x * blockDim.x;
    for (int i = blockIdx.x * blockDim.x + threadIdx.x; i < E; i += stride)
        atomicAdd(&deg[col[i]], 1.0f);
}
__global__ void fb_dinv(float* __restrict__ d, int N) {
    int i = blockIdx.x * blockDim.x + threadIdx.x;
    if (i < N) d[i] = rsqrtf(d[i] + 1.0f);
}
__global__ void fb_h1p(const float* __restrict__ x, const float* __restrict__ W1, float* __restrict__ h1p, int N) {
    __shared__ float sW[144];
    if (threadIdx.x < 144) sW[threadIdx.x] = W1[threadIdx.x];
    __syncthreads();
    int i = blockIdx.x * blockDim.x + threadIdx.x;
    if (i >= N) return;
    float xi[9];
#pragma unroll
    for (int q = 0; q < 9; ++q) xi[q] = x[i * 9 + q];
#pragma unroll
    for (int ff = 0; ff < 16; ++ff) {
        float a = 0.f;
#pragma unroll
        for (int q = 0; q < 9; ++q) a = fmaf(xi[q], sW[q * 16 + ff], a);
        h1p[i * 16 + ff] = a;
    }
}
__global__ void fb_sc1(const int* __restrict__ row, const int* __restrict__ col, const float* __restrict__ dinv,
                       const float* __restrict__ h1p, float* __restrict__ agg1, long total) {
    long stride = (long)gridDim.x * blockDim.x;
    for (long t = (long)blockIdx.x * blockDim.x + threadIdx.x; t < total; t += stride) {
        int e = (int)(t >> 4), ff = (int)(t & 15);
        int r = row[e], c = col[e];
        atomicAdd(&agg1[c * 16 + ff], h1p[r * 16 + ff] * dinv[r] * dinv[c]);
    }
}
__global__ void fb_fin1(const float* __restrict__ agg1, const float* __restrict__ h1p, const float* __restrict__ dinv,
                        const float* __restrict__ b1, const float* __restrict__ W2, float* __restrict__ h2p, int N) {
    __shared__ float sW2[16], sb1[16];
    if (threadIdx.x < 16) { sW2[threadIdx.x] = W2[threadIdx.x]; sb1[threadIdx.x] = b1[threadIdx.x]; }
    __syncthreads();
    int i = blockIdx.x * blockDim.x + threadIdx.x;
    if (i >= N) return;
    float di = dinv[i], self = di * di, a = 0.f;
#pragma unroll
    for (int ff = 0; ff < 16; ++ff) {
        float v = agg1[i * 16 + ff] + h1p[i * 16 + ff] * self + sb1[ff];
        a = fmaf(fmaxf(v, 0.f), sW2[ff], a);
    }
    h2p[i] = a;
}
__global__ void fb_sc2(const int* __restrict__ row, const int* __restrict__ col, const float* __restrict__ dinv,
                       const float* __restrict__ h2p, float* __restrict__ out, int E) {
    int stride = gridDim.x * blockDim.x;
    for (int e = blockIdx.x * blockDim.x + threadIdx.x; e < E; e += stride) {
        int r = row[e], c = col[e];
        atomicAdd(&out[c], h2p[r] * dinv[r] * dinv[c]);
    }
}
__global__ void fb_fin2(float* __restrict__ out, const float* __restrict__ h2p, const float* __restrict__ dinv,
                        const float* __restrict__ b2, int N) {
    int i = blockIdx.x * blockDim.x + threadIdx.x;
    if (i < N) {
        float di = dinv[i];
        out[i] = fmaxf(out[i] + h2p[i] * di * di + b2[0], 0.f);
    }
}

// ============================ launcher ============================

extern "C" void kernel_launch(void* const* d_in, const int* in_sizes, int n_in,
                              void* d_out, int out_size, void* d_ws, size_t ws_size,
                              hipStream_t stream) {
    const float* x  = (const float*)d_in[0];
    const int*   ei = (const int*)d_in[1];
    const float* W1 = (const float*)d_in[2];
    const float* b1 = (const float*)d_in[3];
    const float* W2 = (const float*)d_in[4];
    const float* b2 = (const float*)d_in[5];
    float* out = (float*)d_out;
    const int* row = ei;
    const int* col = ei + NE;
    char* ws = (char*)d_ws;

    constexpr size_t OFF_EB = 0;                       // 25,600,000 B
    constexpr size_t OFF_X  = 25600000;                // 3,201,024 B (TOTBINS ints, in-place hist/scan/offsets)
    constexpr size_t OFF_CT = OFF_X + 3201024;         // 4096 B
    constexpr size_t OFF_CB = OFF_CT + 4096;           // 4096 B
    constexpr size_t OFF_DI = OFF_CB + 4096;           // 400,128 B
    constexpr size_t OFF_G1 = OFF_DI + 400128;         // 6,400,000 B
    constexpr size_t OFF_GG = OFF_G1 + 6400000;        // 400,000 B
    constexpr size_t WS_NEED = OFF_GG + 400000;        // ~36.0 MB

    if (ws_size >= WS_NEED) {
        int*   eb    = (int*)(ws + OFF_EB);
        int*   X     = (int*)(ws + OFF_X);
        int*   ctot  = (int*)(ws + OFF_CT);
        int*   cbase = (int*)(ws + OFF_CB);
        float* dinv  = (float*)(ws + OFF_DI);
        float* g1    = (float*)(ws + OFF_G1);
        float* gg    = (float*)(ws + OFF_GG);

        histA<<<NB, 512, 0, stream>>>(col, X);
        scan1<<<NCH, 256, 0, stream>>>(X, ctot);
        scan2<<<1, 1024, 0, stream>>>(ctot, cbase);
        scan3<<<(TOTBINS + 255) / 256, 256, 0, stream>>>(X, cbase);
        passB<<<NB, 512, 0, stream>>>(row, col, X, eb);
        passC<<<NBKT, 256, 0, stream>>>(eb, X, x, W1, dinv, g1);
        passE<<<NBKT, 256, 0, stream>>>(eb, X, g1, dinv, b1, W2, gg);
        passF<<<NBKT, 256, 0, stream>>>(eb, X, gg, dinv, b2, out);
    } else {
        // fallback: global-atomic version (needs ~13.8 MB)
        float* dinv = (float*)(ws);
        float* h1p  = (float*)(ws + 524288);
        float* agg1 = (float*)(ws + 6924288);
        float* h2p  = (float*)(ws + 13324288);
        hipMemsetAsync(dinv, 0, NN * sizeof(float), stream);
        hipMemsetAsync(agg1, 0, NN * 16 * sizeof(float), stream);
        hipMemsetAsync(out, 0, NN * sizeof(float), stream);
        const int B = 256;
        int gridN = (NN + B - 1) / B;
        fb_deg<<<4096, B, 0, stream>>>(col, dinv, NE);
        fb_dinv<<<gridN, B, 0, stream>>>(dinv, NN);
        fb_h1p<<<gridN, B, 0, stream>>>(x, W1, h1p, NN);
        fb_sc1<<<8192, B, 0, stream>>>(row, col, dinv, h1p, agg1, (long)NE * 16);
        fb_fin1<<<gridN, B, 0, stream>>>(agg1, h1p, dinv, b1, W2, h2p, NN);
        fb_sc2<<<4096, B, 0, stream>>>(row, col, dinv, h2p, out, NE);
        fb_fin2<<<gridN, B, 0, stream>>>(out, h2p, dinv, b2, NN);
    }
}